// Round 1
// baseline (467.072 us; speedup 1.0000x reference)
//
#include <hip/hip_runtime.h>
#include <hip/hip_bf16.h>

// B=4, T=1024, E=512, H=8.  All matmuls expressed as C = alpha*A.B^T (+bias),
// A:[M,K] lda, B:[N,K] ldb, C:[M,N] ldc, bf16 in / fp32 accum.
// Layouts:
//   Q,K  : [b,t,h,e] (= x@W^T natural row-major, ldc=4096); per-(b,h) view lda=4096
//   Vt   : [h*e, b*t] = Wv @ x^T  (V pre-transposed via operand swap)
//   S/P  : [b,h,q,k]  (softmax in place, wave per row)
//   O    : [b,t,h*e]  (PV epilogue writes strided -> ready for out GEMM)

typedef short bf16x8 __attribute__((ext_vector_type(8)));
typedef float f32x4 __attribute__((ext_vector_type(4)));
typedef unsigned short u16x8 __attribute__((ext_vector_type(8)));

__device__ __forceinline__ unsigned short f2bf(float f) {
  unsigned int u = __float_as_uint(f);
  u += 0x7FFFu + ((u >> 16) & 1u);            // RNE, finite inputs
  return (unsigned short)(u >> 16);
}
__device__ __forceinline__ float bf2f(unsigned short s) {
  return __uint_as_float(((unsigned int)s) << 16);
}

typedef const __attribute__((address_space(1))) unsigned int* gas1_t;
typedef __attribute__((address_space(3))) unsigned int* las3_t;

__device__ __forceinline__ void gload16(const unsigned short* g, unsigned short* l) {
  __builtin_amdgcn_global_load_lds((gas1_t)g, (las3_t)l, 16, 0, 0);
}

__device__ __forceinline__ void store_val(unsigned short* p, float v) { *p = f2bf(v); }
__device__ __forceinline__ void store_val(float* p, float v) { *p = v; }

// ---------------- generic BT GEMM, 128x128 tile, BK=32, 4 waves ----------------
// LDS is fragment-major: slot s (16B = 8 bf16) holds rows (s>>6)*16+(lane&15),
// k-chunk ((lane>>4)&3)*8 -- so global_load_lds stages linearly AND ds_read_b128
// of a fragment is 64 consecutive 16B slots (conflict-free).
template<typename OutT, bool HAS_BIAS>
__global__ __launch_bounds__(256) void gemm_bt(
    const unsigned short* __restrict__ A, const unsigned short* __restrict__ B,
    OutT* __restrict__ C, const float* __restrict__ bias,
    int K, int lda, int ldb, int ldc,
    long long sAb, long long sAh, long long sBb, long long sBh,
    long long sCb, long long sCh, float alpha)
{
  const int tid  = threadIdx.x;
  const int lane = tid & 63;
  const int wave = tid >> 6;
  const int wr = wave >> 1, wc = wave & 1;
  const int bb = blockIdx.z >> 3, hh = blockIdx.z & 7;
  const long long m0 = (long long)blockIdx.y * 128;
  const long long n0 = (long long)blockIdx.x * 128;

  const unsigned short* Ab = A + bb * sAb + hh * sAh;
  const unsigned short* Bb = B + bb * sBb + hh * sBh;

  __shared__ __align__(16) unsigned short lds[8192];   // A: [0,4096), B: [4096,8192)

  const int srow = wave * 16 + (tid & 15);             // staging row (call 0)
  const int skc  = ((tid >> 4) & 3) * 8;               // staging k-chunk
  const unsigned short* gA = Ab + (size_t)(m0 + srow) * lda + skc;
  const unsigned short* gB = Bb + (size_t)(n0 + srow) * ldb + skc;
  const size_t aStep = (size_t)64 * lda;
  const size_t bStep = (size_t)64 * ldb;
  unsigned short* lA = lds + wave * 512;               // wave-uniform LDS base
  unsigned short* lB = lds + 4096 + wave * 512;

  f32x4 acc[4][4];
#pragma unroll
  for (int m = 0; m < 4; ++m)
#pragma unroll
    for (int n = 0; n < 4; ++n) acc[m][n] = (f32x4){0.f, 0.f, 0.f, 0.f};

  for (int k0 = 0; k0 < K; k0 += 32) {
    gload16(gA + k0,         lA);          // rows  0..63 of A tile
    gload16(gA + aStep + k0, lA + 2048);   // rows 64..127
    gload16(gB + k0,         lB);
    gload16(gB + bStep + k0, lB + 2048);
    __syncthreads();                        // drains vmcnt(0) before barrier

    bf16x8 af[4], bf[4];
    const bf16x8* sA = (const bf16x8*)lds;
    const bf16x8* sB = (const bf16x8*)(lds + 4096);
#pragma unroll
    for (int m = 0; m < 4; ++m) af[m] = sA[(wr * 4 + m) * 64 + lane];
#pragma unroll
    for (int n = 0; n < 4; ++n) bf[n] = sB[(wc * 4 + n) * 64 + lane];
#pragma unroll
    for (int m = 0; m < 4; ++m)
#pragma unroll
      for (int n = 0; n < 4; ++n)
        acc[m][n] = __builtin_amdgcn_mfma_f32_16x16x32_bf16(af[m], bf[n], acc[m][n], 0, 0, 0);
    __syncthreads();
  }

  // C/D layout (m89/m91 verified): col = lane&15, row = (lane>>4)*4 + reg
  OutT* Cb = C + bb * sCb + hh * sCh;
  const int r0 = (lane >> 4) * 4;
  const int cc = lane & 15;
#pragma unroll
  for (int m = 0; m < 4; ++m) {
#pragma unroll
    for (int n = 0; n < 4; ++n) {
      const long long col = n0 + wc * 64 + n * 16 + cc;
      const float bv = HAS_BIAS ? bias[col] : 0.0f;
#pragma unroll
      for (int r = 0; r < 4; ++r) {
        const long long row = m0 + wr * 64 + m * 16 + r0 + r;
        store_val(Cb + (size_t)row * ldc + col, acc[m][n][r] * alpha + bv);
      }
    }
  }
}

// ---------------- fp32 -> bf16 cast ----------------
__global__ __launch_bounds__(256) void cast_kernel(
    const float* __restrict__ in, unsigned short* __restrict__ out, int n4)
{
  int i = blockIdx.x * 256 + threadIdx.x;
  if (i >= n4) return;
  float4 v = ((const float4*)in)[i];
  ushort4 o;
  o.x = f2bf(v.x); o.y = f2bf(v.y); o.z = f2bf(v.z); o.w = f2bf(v.w);
  ((ushort4*)out)[i] = o;
}

// ---------------- in-place row softmax over S (bf16), logit = S - mask ----------------
// one wave per 1024-wide row; 4 rows per block. S layout [b,h,q,k]; mask [b,q,k].
__global__ __launch_bounds__(256) void softmax_kernel(
    unsigned short* __restrict__ S, const float* __restrict__ mask)
{
  const int wave = threadIdx.x >> 6;
  const int lane = threadIdx.x & 63;
  const long long row = (long long)blockIdx.x * 4 + wave;   // 0..32767
  const int q = (int)(row & 1023);
  const int b = (int)(row >> 13);                            // (row>>10)>>3
  unsigned short* Srow = S + row * 1024;
  const float* mrow = mask + ((size_t)b * 1024 + q) * 1024;

  u16x8 sv0 = ((const u16x8*)Srow)[lane * 2];
  u16x8 sv1 = ((const u16x8*)Srow)[lane * 2 + 1];
  float mk[16];
  const float4* m4 = (const float4*)mrow + lane * 4;
#pragma unroll
  for (int t = 0; t < 4; ++t) {
    float4 v = m4[t];
    mk[t * 4 + 0] = v.x; mk[t * 4 + 1] = v.y; mk[t * 4 + 2] = v.z; mk[t * 4 + 3] = v.w;
  }

  float lg[16];
#pragma unroll
  for (int j = 0; j < 8; ++j) lg[j] = bf2f(sv0[j]) - mk[j];
#pragma unroll
  for (int j = 0; j < 8; ++j) lg[8 + j] = bf2f(sv1[j]) - mk[8 + j];

  float mx = lg[0];
#pragma unroll
  for (int j = 1; j < 16; ++j) mx = fmaxf(mx, lg[j]);
#pragma unroll
  for (int off = 32; off > 0; off >>= 1) mx = fmaxf(mx, __shfl_xor(mx, off));

  float ex[16], sm = 0.f;
#pragma unroll
  for (int j = 0; j < 16; ++j) { ex[j] = __expf(lg[j] - mx); sm += ex[j]; }
#pragma unroll
  for (int off = 32; off > 0; off >>= 1) sm += __shfl_xor(sm, off);
  const float rinv = 1.0f / sm;

  u16x8 o0, o1;
#pragma unroll
  for (int j = 0; j < 8; ++j) o0[j] = f2bf(ex[j] * rinv);
#pragma unroll
  for (int j = 0; j < 8; ++j) o1[j] = f2bf(ex[8 + j] * rinv);
  ((u16x8*)Srow)[lane * 2] = o0;
  ((u16x8*)Srow)[lane * 2 + 1] = o1;
}

extern "C" void kernel_launch(void* const* d_in, const int* in_sizes, int n_in,
                              void* d_out, int out_size, void* d_ws, size_t ws_size,
                              hipStream_t stream) {
  const float* x    = (const float*)d_in[0];
  const float* mask = (const float*)d_in[1];
  const float* Wk   = (const float*)d_in[2];
  const float* Wq   = (const float*)d_in[3];
  const float* Wv   = (const float*)d_in[4];
  const float* Wu   = (const float*)d_in[5];
  const float* bu   = (const float*)d_in[6];

  const size_t MB = 1024 * 1024;
  if (ws_size < 212 * MB) return;   // need 212MB scratch
  char* ws = (char*)d_ws;
  unsigned short* xb  = (unsigned short*)(ws + 0 * MB);    // 4MB  [4096,512]
  unsigned short* Wqb = (unsigned short*)(ws + 4 * MB);    // 4MB  [4096,512]
  unsigned short* Wkb = (unsigned short*)(ws + 8 * MB);    // 4MB
  unsigned short* Wvb = (unsigned short*)(ws + 12 * MB);   // 4MB
  unsigned short* Wub = (unsigned short*)(ws + 16 * MB);   // 4MB  [512,4096]
  unsigned short* Qb  = (unsigned short*)(ws + 20 * MB);   // 32MB [b,t,h,e]
  unsigned short* Kb  = (unsigned short*)(ws + 52 * MB);   // 32MB
  unsigned short* Vt  = (unsigned short*)(ws + 84 * MB);   // 32MB [h*e, b*t]
  unsigned short* Sb  = (unsigned short*)(ws + 116 * MB);  // 64MB [b,h,q,k]
  unsigned short* Ob  = (unsigned short*)(ws + 180 * MB);  // 32MB [b,t,h*e]

  cast_kernel<<<2048, 256, 0, stream>>>(x,  xb,  524288);
  cast_kernel<<<2048, 256, 0, stream>>>(Wq, Wqb, 524288);
  cast_kernel<<<2048, 256, 0, stream>>>(Wk, Wkb, 524288);
  cast_kernel<<<2048, 256, 0, stream>>>(Wv, Wvb, 524288);
  cast_kernel<<<2048, 256, 0, stream>>>(Wu, Wub, 524288);

  // Q = x.Wq^T, K = x.Wk^T   (M=N=4096, K=512)
  gemm_bt<unsigned short, false><<<dim3(32, 32, 1), 256, 0, stream>>>(
      xb, Wqb, Qb, nullptr, 512, 512, 512, 4096, 0, 0, 0, 0, 0, 0, 1.0f);
  gemm_bt<unsigned short, false><<<dim3(32, 32, 1), 256, 0, stream>>>(
      xb, Wkb, Kb, nullptr, 512, 512, 512, 4096, 0, 0, 0, 0, 0, 0, 1.0f);
  // Vt = Wv.x^T  (V pre-transposed: [h*e, b*t])
  gemm_bt<unsigned short, false><<<dim3(32, 32, 1), 256, 0, stream>>>(
      Wvb, xb, Vt, nullptr, 512, 512, 512, 4096, 0, 0, 0, 0, 0, 0, 1.0f);
  // S = (1/sqrt(512)) * Q.K^T per (b,h)   (M=N=1024, K=512, 32 batches)
  gemm_bt<unsigned short, false><<<dim3(8, 8, 32), 256, 0, stream>>>(
      Qb, Kb, Sb, nullptr, 512, 4096, 4096, 1024,
      4194304LL, 512LL, 4194304LL, 512LL, 8388608LL, 1048576LL,
      0.044194173824159216f);
  // P = softmax(S - mask) in place
  softmax_kernel<<<8192, 256, 0, stream>>>(Sb, mask);
  // O = P.V  (B operand = Vt rows, per-(b,h) base h*512*4096 + b*1024)
  gemm_bt<unsigned short, false><<<dim3(4, 8, 32), 256, 0, stream>>>(
      Sb, Vt, Ob, nullptr, 1024, 1024, 4096, 4096,
      8388608LL, 1048576LL, 1024LL, 2097152LL, 4194304LL, 512LL, 1.0f);
  // out = O.Wu^T + bu   (M=4096, N=512, K=4096)
  gemm_bt<float, true><<<dim3(4, 32, 1), 256, 0, stream>>>(
      Ob, Wub, (float*)d_out, bu, 4096, 4096, 4096, 512,
      0, 0, 0, 0, 0, 0, 1.0f);
}

// Round 2
// 410.610 us; speedup vs baseline: 1.1375x; 1.1375x over previous
//
#include <hip/hip_runtime.h>
#include <hip/hip_bf16.h>

// B=4, T=1024, E=512, H=8.  All matmuls expressed as C = alpha*A.B^T (+bias),
// A:[M,K] lda, B:[N,K] ldb, C:[M,N] ldc, bf16 in / fp32 accum.
// Layouts:
//   Q,K  : [b,t,h,e] (= x@W^T natural row-major, ldc=4096); per-(b,h) view lda=4096
//   Vt   : [h*e, b*t] = Wv @ x^T  (V pre-transposed via operand swap)
//   S/P  : [b,h,q,k]  (softmax in place, wave per row)
//   O    : [b,t,h*e]  (PV epilogue writes strided -> ready for out GEMM)
// Out GEMM (M=4096,N=512,K=4096) is split-K=8 (128 blocks -> 1024) + reduce.

typedef short bf16x8 __attribute__((ext_vector_type(8)));
typedef float f32x4 __attribute__((ext_vector_type(4)));
typedef unsigned short u16x8 __attribute__((ext_vector_type(8)));

__device__ __forceinline__ unsigned short f2bf(float f) {
  unsigned int u = __float_as_uint(f);
  u += 0x7FFFu + ((u >> 16) & 1u);            // RNE, finite inputs
  return (unsigned short)(u >> 16);
}
__device__ __forceinline__ float bf2f(unsigned short s) {
  return __uint_as_float(((unsigned int)s) << 16);
}

typedef const __attribute__((address_space(1))) unsigned int* gas1_t;
typedef __attribute__((address_space(3))) unsigned int* las3_t;

__device__ __forceinline__ void gload16(const unsigned short* g, unsigned short* l) {
  __builtin_amdgcn_global_load_lds((gas1_t)g, (las3_t)l, 16, 0, 0);
}

__device__ __forceinline__ void store_val(unsigned short* p, float v) { *p = f2bf(v); }
__device__ __forceinline__ void store_val(float* p, float v) { *p = v; }

// ---------------- generic BT GEMM, 128x128 tile, BK=32, 4 waves ----------------
// LDS is fragment-major: slot s (16B = 8 bf16) holds rows (s>>6)*16+(lane&15),
// k-chunk ((lane>>4)&3)*8 -- so global_load_lds stages linearly AND ds_read_b128
// of a fragment is 64 consecutive 16B slots (conflict-free).
// blockIdx.z decomposes as bb = z >> zshift, hh = z & ((1<<zshift)-1).
//   * batched attention GEMMs: zshift=3 (bb=batch, hh=head)
//   * split-K: zshift=0, bb = K-slice index, sAb/sBb = k-offset, sCb = M*N.
template<typename OutT, bool HAS_BIAS>
__global__ __launch_bounds__(256) void gemm_bt(
    const unsigned short* __restrict__ A, const unsigned short* __restrict__ B,
    OutT* __restrict__ C, const float* __restrict__ bias,
    int K, int lda, int ldb, int ldc, int zshift,
    long long sAb, long long sAh, long long sBb, long long sBh,
    long long sCb, long long sCh, float alpha)
{
  const int tid  = threadIdx.x;
  const int lane = tid & 63;
  const int wave = tid >> 6;
  const int wr = wave >> 1, wc = wave & 1;
  const int bb = blockIdx.z >> zshift, hh = blockIdx.z & ((1 << zshift) - 1);
  const long long m0 = (long long)blockIdx.y * 128;
  const long long n0 = (long long)blockIdx.x * 128;

  const unsigned short* Ab = A + bb * sAb + hh * sAh;
  const unsigned short* Bb = B + bb * sBb + hh * sBh;

  __shared__ __align__(16) unsigned short lds[8192];   // A: [0,4096), B: [4096,8192)

  const int srow = wave * 16 + (tid & 15);             // staging row (call 0)
  const int skc  = ((tid >> 4) & 3) * 8;               // staging k-chunk
  const unsigned short* gA = Ab + (size_t)(m0 + srow) * lda + skc;
  const unsigned short* gB = Bb + (size_t)(n0 + srow) * ldb + skc;
  const size_t aStep = (size_t)64 * lda;
  const size_t bStep = (size_t)64 * ldb;
  unsigned short* lA = lds + wave * 512;               // wave-uniform LDS base
  unsigned short* lB = lds + 4096 + wave * 512;

  f32x4 acc[4][4];
#pragma unroll
  for (int m = 0; m < 4; ++m)
#pragma unroll
    for (int n = 0; n < 4; ++n) acc[m][n] = (f32x4){0.f, 0.f, 0.f, 0.f};

  for (int k0 = 0; k0 < K; k0 += 32) {
    gload16(gA + k0,         lA);          // rows  0..63 of A tile
    gload16(gA + aStep + k0, lA + 2048);   // rows 64..127
    gload16(gB + k0,         lB);
    gload16(gB + bStep + k0, lB + 2048);
    __syncthreads();                        // drains vmcnt(0) before barrier

    bf16x8 af[4], bf[4];
    const bf16x8* sA = (const bf16x8*)lds;
    const bf16x8* sB = (const bf16x8*)(lds + 4096);
#pragma unroll
    for (int m = 0; m < 4; ++m) af[m] = sA[(wr * 4 + m) * 64 + lane];
#pragma unroll
    for (int n = 0; n < 4; ++n) bf[n] = sB[(wc * 4 + n) * 64 + lane];
#pragma unroll
    for (int m = 0; m < 4; ++m)
#pragma unroll
      for (int n = 0; n < 4; ++n)
        acc[m][n] = __builtin_amdgcn_mfma_f32_16x16x32_bf16(af[m], bf[n], acc[m][n], 0, 0, 0);
    __syncthreads();
  }

  // C/D layout (m89/m91 verified): col = lane&15, row = (lane>>4)*4 + reg
  OutT* Cb = C + bb * sCb + hh * sCh;
  const int r0 = (lane >> 4) * 4;
  const int cc = lane & 15;
#pragma unroll
  for (int m = 0; m < 4; ++m) {
#pragma unroll
    for (int n = 0; n < 4; ++n) {
      const long long col = n0 + wc * 64 + n * 16 + cc;
      const float bv = HAS_BIAS ? bias[col] : 0.0f;
#pragma unroll
      for (int r = 0; r < 4; ++r) {
        const long long row = m0 + wr * 64 + m * 16 + r0 + r;
        store_val(Cb + (size_t)row * ldc + col, acc[m][n][r] * alpha + bv);
      }
    }
  }
}

// ---------------- split-K reduce: out = sum(partials) + bias ----------------
// partials: 8 x [4096,512] fp32; out: [4096,512] fp32. One float4 per thread.
__global__ __launch_bounds__(256) void reduce_kernel(
    const float* __restrict__ P, const float* __restrict__ bias,
    float* __restrict__ out)
{
  const int i = blockIdx.x * 256 + threadIdx.x;      // 0..524287 float4s
  const int col4 = i & 127;                           // 512/4 float4s per row
  const float4* p4 = (const float4*)P + i;
  float4 s = p4[0];
#pragma unroll
  for (int z = 1; z < 8; ++z) {
    float4 v = p4[(size_t)z * 524288];
    s.x += v.x; s.y += v.y; s.z += v.z; s.w += v.w;
  }
  float4 b = ((const float4*)bias)[col4];
  s.x += b.x; s.y += b.y; s.z += b.z; s.w += b.w;
  ((float4*)out)[i] = s;
}

// ---------------- fused fp32 -> bf16 cast of all 5 tensors ----------------
// dst is contiguous in ws: [x | Wq | Wk | Wv | Wu], each 2M elems (524288 float4).
__global__ __launch_bounds__(256) void cast5_kernel(
    const float* __restrict__ s0, const float* __restrict__ s1,
    const float* __restrict__ s2, const float* __restrict__ s3,
    const float* __restrict__ s4, unsigned short* __restrict__ dst)
{
  const int seg = blockIdx.x >> 11;                   // 2048 blocks per segment
  const int off = (blockIdx.x & 2047) * 256 + threadIdx.x;
  const float* s = s0;
  if (seg == 1) s = s1; else if (seg == 2) s = s2;
  else if (seg == 3) s = s3; else if (seg == 4) s = s4;
  float4 v = ((const float4*)s)[off];
  ushort4 o;
  o.x = f2bf(v.x); o.y = f2bf(v.y); o.z = f2bf(v.z); o.w = f2bf(v.w);
  ((ushort4*)dst)[(size_t)seg * 524288 + off] = o;
}

// ---------------- in-place row softmax over S (bf16), logit = S - mask ----------------
// one wave per 1024-wide row; 4 rows per block. S layout [b,h,q,k]; mask [b,q,k].
__global__ __launch_bounds__(256) void softmax_kernel(
    unsigned short* __restrict__ S, const float* __restrict__ mask)
{
  const int wave = threadIdx.x >> 6;
  const int lane = threadIdx.x & 63;
  const long long row = (long long)blockIdx.x * 4 + wave;   // 0..32767
  const int q = (int)(row & 1023);
  const int b = (int)(row >> 13);                            // (row>>10)>>3
  unsigned short* Srow = S + row * 1024;
  const float* mrow = mask + ((size_t)b * 1024 + q) * 1024;

  u16x8 sv0 = ((const u16x8*)Srow)[lane * 2];
  u16x8 sv1 = ((const u16x8*)Srow)[lane * 2 + 1];
  float mk[16];
  const float4* m4 = (const float4*)mrow + lane * 4;
#pragma unroll
  for (int t = 0; t < 4; ++t) {
    float4 v = m4[t];
    mk[t * 4 + 0] = v.x; mk[t * 4 + 1] = v.y; mk[t * 4 + 2] = v.z; mk[t * 4 + 3] = v.w;
  }

  float lg[16];
#pragma unroll
  for (int j = 0; j < 8; ++j) lg[j] = bf2f(sv0[j]) - mk[j];
#pragma unroll
  for (int j = 0; j < 8; ++j) lg[8 + j] = bf2f(sv1[j]) - mk[8 + j];

  float mx = lg[0];
#pragma unroll
  for (int j = 1; j < 16; ++j) mx = fmaxf(mx, lg[j]);
#pragma unroll
  for (int off = 32; off > 0; off >>= 1) mx = fmaxf(mx, __shfl_xor(mx, off));

  float ex[16], sm = 0.f;
#pragma unroll
  for (int j = 0; j < 16; ++j) { ex[j] = __expf(lg[j] - mx); sm += ex[j]; }
#pragma unroll
  for (int off = 32; off > 0; off >>= 1) sm += __shfl_xor(sm, off);
  const float rinv = 1.0f / sm;

  u16x8 o0, o1;
#pragma unroll
  for (int j = 0; j < 8; ++j) o0[j] = f2bf(ex[j] * rinv);
#pragma unroll
  for (int j = 0; j < 8; ++j) o1[j] = f2bf(ex[8 + j] * rinv);
  ((u16x8*)Srow)[lane * 2] = o0;
  ((u16x8*)Srow)[lane * 2 + 1] = o1;
}

extern "C" void kernel_launch(void* const* d_in, const int* in_sizes, int n_in,
                              void* d_out, int out_size, void* d_ws, size_t ws_size,
                              hipStream_t stream) {
  const float* x    = (const float*)d_in[0];
  const float* mask = (const float*)d_in[1];
  const float* Wk   = (const float*)d_in[2];
  const float* Wq   = (const float*)d_in[3];
  const float* Wv   = (const float*)d_in[4];
  const float* Wu   = (const float*)d_in[5];
  const float* bu   = (const float*)d_in[6];

  const size_t MB = 1024 * 1024;
  if (ws_size < 212 * MB) return;   // need 212MB scratch
  char* ws = (char*)d_ws;
  unsigned short* xb  = (unsigned short*)(ws + 0 * MB);    // 4MB  [4096,512]
  unsigned short* Wqb = (unsigned short*)(ws + 4 * MB);    // 4MB  [4096,512]
  unsigned short* Wkb = (unsigned short*)(ws + 8 * MB);    // 4MB
  unsigned short* Wvb = (unsigned short*)(ws + 12 * MB);   // 4MB
  unsigned short* Wub = (unsigned short*)(ws + 16 * MB);   // 4MB  [512,4096]
  unsigned short* Qb  = (unsigned short*)(ws + 20 * MB);   // 32MB [b,t,h,e]
  unsigned short* Kb  = (unsigned short*)(ws + 52 * MB);   // 32MB
  unsigned short* Vt  = (unsigned short*)(ws + 84 * MB);   // 32MB [h*e, b*t]
  unsigned short* Sb  = (unsigned short*)(ws + 116 * MB);  // 64MB [b,h,q,k]
  unsigned short* Ob  = (unsigned short*)(ws + 180 * MB);  // 32MB [b,t,h*e]
  // split-K partials reuse the (dead by then) Qb/Kb region: 8 x 8MB = 64MB
  float* Pk = (float*)(ws + 20 * MB);

  // bf16 casts of x and all weights (dst contiguous at ws[0..20MB))
  cast5_kernel<<<5 * 2048, 256, 0, stream>>>(x, Wq, Wk, Wv, Wu, xb);

  // Q = x.Wq^T, K = x.Wk^T   (M=N=4096, K=512)
  gemm_bt<unsigned short, false><<<dim3(32, 32, 1), 256, 0, stream>>>(
      xb, Wqb, Qb, nullptr, 512, 512, 512, 4096, 3, 0, 0, 0, 0, 0, 0, 1.0f);
  gemm_bt<unsigned short, false><<<dim3(32, 32, 1), 256, 0, stream>>>(
      xb, Wkb, Kb, nullptr, 512, 512, 512, 4096, 3, 0, 0, 0, 0, 0, 0, 1.0f);
  // Vt = Wv.x^T  (V pre-transposed: [h*e, b*t])
  gemm_bt<unsigned short, false><<<dim3(32, 32, 1), 256, 0, stream>>>(
      Wvb, xb, Vt, nullptr, 512, 512, 512, 4096, 3, 0, 0, 0, 0, 0, 0, 1.0f);
  // S = (1/sqrt(512)) * Q.K^T per (b,h)   (M=N=1024, K=512, 32 batches)
  gemm_bt<unsigned short, false><<<dim3(8, 8, 32), 256, 0, stream>>>(
      Qb, Kb, Sb, nullptr, 512, 4096, 4096, 1024, 3,
      4194304LL, 512LL, 4194304LL, 512LL, 8388608LL, 1048576LL,
      0.044194173824159216f);
  // P = softmax(S - mask) in place
  softmax_kernel<<<8192, 256, 0, stream>>>(Sb, mask);
  // O = P.V  (B operand = Vt rows, per-(b,h) base h*512*4096 + b*1024)
  gemm_bt<unsigned short, false><<<dim3(4, 8, 32), 256, 0, stream>>>(
      Sb, Vt, Ob, nullptr, 1024, 1024, 4096, 4096, 3,
      8388608LL, 1048576LL, 1024LL, 2097152LL, 4194304LL, 512LL, 1.0f);
  // out partials: Pk[z] = Ob[:, z*512:(z+1)*512] . Wub[:, z*512:(z+1)*512]^T
  // (M=4096, N=512, K-slice=512, 8 slices -> 1024 blocks)
  gemm_bt<float, false><<<dim3(4, 32, 8), 256, 0, stream>>>(
      Ob, Wub, Pk, nullptr, 512, 4096, 4096, 512, 0,
      512LL, 0, 512LL, 0, 2097152LL, 0, 1.0f);
  // out = sum_z Pk[z] + bu
  reduce_kernel<<<2048, 256, 0, stream>>>(Pk, bu, (float*)d_out);
}

// Round 3
// 364.815 us; speedup vs baseline: 1.2803x; 1.1255x over previous
//
#include <hip/hip_runtime.h>
#include <hip/hip_bf16.h>

// B=4, T=1024, E=512, H=8.
// Pipeline: cast5 -> Q,K projections + Vt (=Wv.x^T) via gemm_bt ->
//           fused_attn (S=QK^T, softmax(S*a - mask), O=P.V) ->
//           out GEMM split-K=8 + reduce(+bias).
// Layouts:
//   Q,K  : [b,t,h,e] row stride 4096
//   Vt   : [h*e, b*t] (V pre-transposed via operand swap)
//   O    : [b,t,h*e]

typedef short bf16x8 __attribute__((ext_vector_type(8)));
typedef float f32x4 __attribute__((ext_vector_type(4)));

__device__ __forceinline__ unsigned short f2bf(float f) {
  unsigned int u = __float_as_uint(f);
  u += 0x7FFFu + ((u >> 16) & 1u);            // RNE, finite inputs
  return (unsigned short)(u >> 16);
}

typedef const __attribute__((address_space(1))) unsigned int* gas1_t;
typedef __attribute__((address_space(3))) unsigned int* las3_t;

__device__ __forceinline__ void gload16(const unsigned short* g, unsigned short* l) {
  __builtin_amdgcn_global_load_lds((gas1_t)g, (las3_t)l, 16, 0, 0);
}

__device__ __forceinline__ void store_val(unsigned short* p, float v) { *p = f2bf(v); }
__device__ __forceinline__ void store_val(float* p, float v) { *p = v; }

// ---------------- generic BT GEMM, 128x128 tile, BK=32, 4 waves ----------------
template<typename OutT, bool HAS_BIAS>
__global__ __launch_bounds__(256) void gemm_bt(
    const unsigned short* __restrict__ A, const unsigned short* __restrict__ B,
    OutT* __restrict__ C, const float* __restrict__ bias,
    int K, int lda, int ldb, int ldc, int zshift,
    long long sAb, long long sAh, long long sBb, long long sBh,
    long long sCb, long long sCh, float alpha)
{
  const int tid  = threadIdx.x;
  const int lane = tid & 63;
  const int wave = tid >> 6;
  const int wr = wave >> 1, wc = wave & 1;
  const int bb = blockIdx.z >> zshift, hh = blockIdx.z & ((1 << zshift) - 1);
  const long long m0 = (long long)blockIdx.y * 128;
  const long long n0 = (long long)blockIdx.x * 128;

  const unsigned short* Ab = A + bb * sAb + hh * sAh;
  const unsigned short* Bb = B + bb * sBb + hh * sBh;

  __shared__ __align__(16) unsigned short lds[8192];

  const int srow = wave * 16 + (tid & 15);
  const int skc  = ((tid >> 4) & 3) * 8;
  const unsigned short* gA = Ab + (size_t)(m0 + srow) * lda + skc;
  const unsigned short* gB = Bb + (size_t)(n0 + srow) * ldb + skc;
  const size_t aStep = (size_t)64 * lda;
  const size_t bStep = (size_t)64 * ldb;
  unsigned short* lA = lds + wave * 512;
  unsigned short* lB = lds + 4096 + wave * 512;

  f32x4 acc[4][4];
#pragma unroll
  for (int m = 0; m < 4; ++m)
#pragma unroll
    for (int n = 0; n < 4; ++n) acc[m][n] = (f32x4){0.f, 0.f, 0.f, 0.f};

  for (int k0 = 0; k0 < K; k0 += 32) {
    gload16(gA + k0,         lA);
    gload16(gA + aStep + k0, lA + 2048);
    gload16(gB + k0,         lB);
    gload16(gB + bStep + k0, lB + 2048);
    __syncthreads();

    bf16x8 af[4], bf[4];
    const bf16x8* sA = (const bf16x8*)lds;
    const bf16x8* sB = (const bf16x8*)(lds + 4096);
#pragma unroll
    for (int m = 0; m < 4; ++m) af[m] = sA[(wr * 4 + m) * 64 + lane];
#pragma unroll
    for (int n = 0; n < 4; ++n) bf[n] = sB[(wc * 4 + n) * 64 + lane];
#pragma unroll
    for (int m = 0; m < 4; ++m)
#pragma unroll
      for (int n = 0; n < 4; ++n)
        acc[m][n] = __builtin_amdgcn_mfma_f32_16x16x32_bf16(af[m], bf[n], acc[m][n], 0, 0, 0);
    __syncthreads();
  }

  OutT* Cb = C + bb * sCb + hh * sCh;
  const int r0 = (lane >> 4) * 4;
  const int cc = lane & 15;
#pragma unroll
  for (int m = 0; m < 4; ++m) {
#pragma unroll
    for (int n = 0; n < 4; ++n) {
      const long long col = n0 + wc * 64 + n * 16 + cc;
      const float bv = HAS_BIAS ? bias[col] : 0.0f;
#pragma unroll
      for (int r = 0; r < 4; ++r) {
        const long long row = m0 + wr * 64 + m * 16 + r0 + r;
        store_val(Cb + (size_t)row * ldc + col, acc[m][n][r] * alpha + bv);
      }
    }
  }
}

// ---------------- fused attention: one block = one (b,h) x 64 q-rows ----------------
// 8 waves/block; wave w owns keys [w*128,(w+1)*128) in phase 1 and
// e-cols [w*64,(w+1)*64) in phase 2. LDS: Q frag-major [0,32768) elems,
// P frag-major overlay [0,65536) elems, f32 scratch at [65536,..).
__global__ __launch_bounds__(512, 2) void fused_attn(
    const unsigned short* __restrict__ Q, const unsigned short* __restrict__ K,
    const unsigned short* __restrict__ Vt, const float* __restrict__ mask,
    unsigned short* __restrict__ O)
{
  const int tid  = threadIdx.x;
  const int lane = tid & 63, wave = tid >> 6;
  const int l15 = lane & 15, lhi = lane >> 4;
  const int orig = blockIdx.x;
  const int swz = (orig & 7) * 64 + (orig >> 3);      // XCD swizzle (512 % 8 == 0)
  const int bh = swz >> 4, qblk = swz & 15;
  const int b = bh >> 3, h = bh & 7;
  const int q0 = qblk * 64;

  __shared__ __align__(16) unsigned short lds[66688];   // 133376 B
  float* sc = (float*)(lds + 65536);                    // [0,512): partials, [512,576): finals

  // ---- stage Q tile 64x512 fragment-major: block (m*16+es), slot=lane ----
#pragma unroll
  for (int c = 0; c < 8; ++c) {
    const int blk = c * 8 + wave;
    const int m = blk >> 4, es = blk & 15;
    const unsigned short* g = Q + ((size_t)(b * 1024 + q0 + m * 16 + l15)) * 4096
                                + h * 512 + es * 32 + lhi * 8;
    gload16(g, lds + blk * 512);
  }
  __syncthreads();

  // ---- phase 1: S = Q.K^T (K-fragments direct global->reg, no reuse) ----
  const unsigned short* kp[8];
#pragma unroll
  for (int j = 0; j < 8; ++j)
    kp[j] = K + ((size_t)(b * 1024 + wave * 128 + j * 16 + l15)) * 4096
              + h * 512 + lhi * 8;

  f32x4 acc[4][8];
#pragma unroll
  for (int m = 0; m < 4; ++m)
#pragma unroll
    for (int j = 0; j < 8; ++j) acc[m][j] = (f32x4){0.f, 0.f, 0.f, 0.f};

  const bf16x8* Ql = (const bf16x8*)lds;
#pragma unroll 4
  for (int es = 0; es < 16; ++es) {
    bf16x8 af[4], bfr[8];
#pragma unroll
    for (int m = 0; m < 4; ++m) af[m] = Ql[(m * 16 + es) * 64 + lane];
#pragma unroll
    for (int j = 0; j < 8; ++j) bfr[j] = *(const bf16x8*)(kp[j] + es * 32);
#pragma unroll
    for (int m = 0; m < 4; ++m)
#pragma unroll
      for (int j = 0; j < 8; ++j)
        acc[m][j] = __builtin_amdgcn_mfma_f32_16x16x32_bf16(af[m], bfr[j], acc[m][j], 0, 0, 0);
  }

  // ---- softmax (exp2 space): logit2 = acc*(a*log2e) - mask*log2e ----
  const float A2 = 0.044194173824159216f * 1.4426950408889634f;
  const float L2E = 1.4426950408889634f;
#pragma unroll
  for (int m = 0; m < 4; ++m)
#pragma unroll
    for (int r = 0; r < 4; ++r) {
      const int q = q0 + m * 16 + lhi * 4 + r;
      const float* mrow = mask + ((size_t)b * 1024 + q) * 1024 + wave * 128 + l15;
#pragma unroll
      for (int j = 0; j < 8; ++j)
        acc[m][j][r] = acc[m][j][r] * A2 - mrow[j * 16] * L2E;
    }

  // per-lane row max over j, then xor-reduce over the 16-lane key group
  float pmax[4][4];
#pragma unroll
  for (int m = 0; m < 4; ++m)
#pragma unroll
    for (int r = 0; r < 4; ++r) {
      float v = acc[m][0][r];
#pragma unroll
      for (int j = 1; j < 8; ++j) v = fmaxf(v, acc[m][j][r]);
      pmax[m][r] = v;
    }
#pragma unroll
  for (int d = 1; d < 16; d <<= 1)
#pragma unroll
    for (int m = 0; m < 4; ++m)
#pragma unroll
      for (int r = 0; r < 4; ++r)
        pmax[m][r] = fmaxf(pmax[m][r], __shfl_xor(pmax[m][r], d));
  if (l15 == 0) {
#pragma unroll
    for (int m = 0; m < 4; ++m)
#pragma unroll
      for (int r = 0; r < 4; ++r)
        sc[(m * 16 + lhi * 4 + r) * 8 + wave] = pmax[m][r];
  }
  __syncthreads();                      // (A) also: all waves done with Q LDS
  {
    float v = sc[tid];                  // row = tid>>3, wave = tid&7
    v = fmaxf(v, __shfl_xor(v, 1));
    v = fmaxf(v, __shfl_xor(v, 2));
    v = fmaxf(v, __shfl_xor(v, 4));
    if ((tid & 7) == 0) sc[512 + (tid >> 3)] = v;
  }
  __syncthreads();                      // (B)

  // ex = exp2(lg - rowmax); partial sums; write P bf16 to LDS (overlays Q)
  float rmax[4][4];
#pragma unroll
  for (int m = 0; m < 4; ++m)
#pragma unroll
    for (int r = 0; r < 4; ++r) rmax[m][r] = sc[512 + m * 16 + lhi * 4 + r];

  float psum[4][4];
#pragma unroll
  for (int m = 0; m < 4; ++m)
#pragma unroll
    for (int r = 0; r < 4; ++r) psum[m][r] = 0.f;

  // P elem addr = lanebase + m*16384 + (j>>1)*512 + (j&1)*256 + r*8
  unsigned short* Pl = lds;
  const int lanebase = lhi * 32 + (l15 >> 3) * 128 + (lane & 7) + wave * 2048;
#pragma unroll
  for (int m = 0; m < 4; ++m)
#pragma unroll
    for (int j = 0; j < 8; ++j)
#pragma unroll
      for (int r = 0; r < 4; ++r) {
        float e = exp2f(acc[m][j][r] - rmax[m][r]);
        psum[m][r] += e;
        Pl[lanebase + m * 16384 + (j >> 1) * 512 + (j & 1) * 256 + r * 8] = f2bf(e);
      }
#pragma unroll
  for (int d = 1; d < 16; d <<= 1)
#pragma unroll
    for (int m = 0; m < 4; ++m)
#pragma unroll
      for (int r = 0; r < 4; ++r)
        psum[m][r] += __shfl_xor(psum[m][r], d);
  if (l15 == 0) {
#pragma unroll
    for (int m = 0; m < 4; ++m)
#pragma unroll
      for (int r = 0; r < 4; ++r)
        sc[(m * 16 + lhi * 4 + r) * 8 + wave] = psum[m][r];
  }
  __syncthreads();                      // (C)
  {
    float v = sc[tid];
    v += __shfl_xor(v, 1);
    v += __shfl_xor(v, 2);
    v += __shfl_xor(v, 4);
    if ((tid & 7) == 0) sc[512 + (tid >> 3)] = 1.0f / v;
  }
  __syncthreads();                      // (D)

  // ---- phase 2: O = P.V ; wave w -> e-cols [w*64,(w+1)*64) ----
  const unsigned short* vp[4];
#pragma unroll
  for (int nf = 0; nf < 4; ++nf)
    vp[nf] = Vt + ((size_t)(h * 512 + wave * 64 + nf * 16 + l15)) * 4096
               + b * 1024 + lhi * 8;

  f32x4 o[4][4];
#pragma unroll
  for (int m = 0; m < 4; ++m)
#pragma unroll
    for (int nf = 0; nf < 4; ++nf) o[m][nf] = (f32x4){0.f, 0.f, 0.f, 0.f};

  const bf16x8* Pl8 = (const bf16x8*)lds;
#pragma unroll 8
  for (int ks = 0; ks < 32; ++ks) {
    bf16x8 pa[4], vb[4];
#pragma unroll
    for (int m = 0; m < 4; ++m) pa[m] = Pl8[(m * 32 + ks) * 64 + lane];
#pragma unroll
    for (int nf = 0; nf < 4; ++nf) vb[nf] = *(const bf16x8*)(vp[nf] + ks * 32);
#pragma unroll
    for (int m = 0; m < 4; ++m)
#pragma unroll
      for (int nf = 0; nf < 4; ++nf)
        o[m][nf] = __builtin_amdgcn_mfma_f32_16x16x32_bf16(pa[m], vb[nf], o[m][nf], 0, 0, 0);
  }

  // epilogue: O /= rowsum; write bf16 to [b,t,h*e]
  float rinv[4][4];
#pragma unroll
  for (int m = 0; m < 4; ++m)
#pragma unroll
    for (int r = 0; r < 4; ++r) rinv[m][r] = sc[512 + m * 16 + lhi * 4 + r];
#pragma unroll
  for (int m = 0; m < 4; ++m)
#pragma unroll
    for (int nf = 0; nf < 4; ++nf)
#pragma unroll
      for (int r = 0; r < 4; ++r) {
        const int q = q0 + m * 16 + lhi * 4 + r;
        const int col = h * 512 + wave * 64 + nf * 16 + l15;
        O[((size_t)(b * 1024 + q)) * 4096 + col] = f2bf(o[m][nf][r] * rinv[m][r]);
      }
}

// ---------------- split-K reduce: out = sum(partials) + bias ----------------
__global__ __launch_bounds__(256) void reduce_kernel(
    const float* __restrict__ P, const float* __restrict__ bias,
    float* __restrict__ out)
{
  const int i = blockIdx.x * 256 + threadIdx.x;
  const int col4 = i & 127;
  const float4* p4 = (const float4*)P + i;
  float4 s = p4[0];
#pragma unroll
  for (int z = 1; z < 8; ++z) {
    float4 v = p4[(size_t)z * 524288];
    s.x += v.x; s.y += v.y; s.z += v.z; s.w += v.w;
  }
  float4 b = ((const float4*)bias)[col4];
  s.x += b.x; s.y += b.y; s.z += b.z; s.w += b.w;
  ((float4*)out)[i] = s;
}

// ---------------- fused fp32 -> bf16 cast of all 5 tensors ----------------
__global__ __launch_bounds__(256) void cast5_kernel(
    const float* __restrict__ s0, const float* __restrict__ s1,
    const float* __restrict__ s2, const float* __restrict__ s3,
    const float* __restrict__ s4, unsigned short* __restrict__ dst)
{
  const int seg = blockIdx.x >> 11;
  const int off = (blockIdx.x & 2047) * 256 + threadIdx.x;
  const float* s = s0;
  if (seg == 1) s = s1; else if (seg == 2) s = s2;
  else if (seg == 3) s = s3; else if (seg == 4) s = s4;
  float4 v = ((const float4*)s)[off];
  ushort4 o;
  o.x = f2bf(v.x); o.y = f2bf(v.y); o.z = f2bf(v.z); o.w = f2bf(v.w);
  ((ushort4*)dst)[(size_t)seg * 524288 + off] = o;
}

extern "C" void kernel_launch(void* const* d_in, const int* in_sizes, int n_in,
                              void* d_out, int out_size, void* d_ws, size_t ws_size,
                              hipStream_t stream) {
  const float* x    = (const float*)d_in[0];
  const float* mask = (const float*)d_in[1];
  const float* Wk   = (const float*)d_in[2];
  const float* Wq   = (const float*)d_in[3];
  const float* Wv   = (const float*)d_in[4];
  const float* Wu   = (const float*)d_in[5];
  const float* bu   = (const float*)d_in[6];

  const size_t MB = 1024 * 1024;
  if (ws_size < 212 * MB) return;
  char* ws = (char*)d_ws;
  unsigned short* xb  = (unsigned short*)(ws + 0 * MB);    // 4MB  [4096,512]
  unsigned short* Wqb = (unsigned short*)(ws + 4 * MB);
  unsigned short* Wkb = (unsigned short*)(ws + 8 * MB);
  unsigned short* Wvb = (unsigned short*)(ws + 12 * MB);
  unsigned short* Wub = (unsigned short*)(ws + 16 * MB);
  unsigned short* Qb  = (unsigned short*)(ws + 20 * MB);   // 32MB [b,t,h,e]
  unsigned short* Kb  = (unsigned short*)(ws + 52 * MB);   // 32MB
  unsigned short* Vt  = (unsigned short*)(ws + 84 * MB);   // 32MB [h*e, b*t]
  unsigned short* Ob  = (unsigned short*)(ws + 180 * MB);  // 32MB [b,t,h*e]
  float* Pk = (float*)(ws + 20 * MB);  // split-K partials overlay Qb/Kb (dead)

  cast5_kernel<<<5 * 2048, 256, 0, stream>>>(x, Wq, Wk, Wv, Wu, xb);

  // Q = x.Wq^T, K = x.Wk^T   (M=N=4096, K=512)
  gemm_bt<unsigned short, false><<<dim3(32, 32, 1), 256, 0, stream>>>(
      xb, Wqb, Qb, nullptr, 512, 512, 512, 4096, 3, 0, 0, 0, 0, 0, 0, 1.0f);
  gemm_bt<unsigned short, false><<<dim3(32, 32, 1), 256, 0, stream>>>(
      xb, Wkb, Kb, nullptr, 512, 512, 512, 4096, 3, 0, 0, 0, 0, 0, 0, 1.0f);
  // Vt = Wv.x^T
  gemm_bt<unsigned short, false><<<dim3(32, 32, 1), 256, 0, stream>>>(
      Wvb, xb, Vt, nullptr, 512, 512, 512, 4096, 3, 0, 0, 0, 0, 0, 0, 1.0f);

  // fused attention: 16 q-blocks x 32 (b,h)
  fused_attn<<<512, 512, 0, stream>>>(Qb, Kb, Vt, mask, Ob);

  // out partials: split-K=8 over K=4096
  gemm_bt<float, false><<<dim3(4, 32, 8), 256, 0, stream>>>(
      Ob, Wub, Pk, nullptr, 512, 4096, 4096, 512, 0,
      512LL, 0, 512LL, 0, 2097152LL, 0, 1.0f);
  reduce_kernel<<<2048, 256, 0, stream>>>(Pk, bu, (float*)d_out);
}